// Round 2
// baseline (916.423 us; speedup 1.0000x reference)
//
#include <hip/hip_runtime.h>

#define N_ 20000
#define E_ 100000

typedef __attribute__((ext_vector_type(8))) short short8;
typedef __attribute__((ext_vector_type(8))) unsigned short ushort8;
typedef __attribute__((ext_vector_type(4))) float f32x4;

__device__ __forceinline__ unsigned short f2bf(float f) {
  union { float f; unsigned u; } v; v.f = f;
  unsigned r = v.u + 0x7fffu + ((v.u >> 16) & 1u);
  return (unsigned short)(r >> 16);
}
__device__ __forceinline__ float bf2f(unsigned short h) {
  union { unsigned u; float f; } v; v.u = ((unsigned)h) << 16;
  return v.f;
}
__device__ __forceinline__ short8 pack8(float4 a, float4 b) {
  short8 v;
  v[0] = (short)f2bf(a.x); v[1] = (short)f2bf(a.y);
  v[2] = (short)f2bf(a.z); v[3] = (short)f2bf(a.w);
  v[4] = (short)f2bf(b.x); v[5] = (short)f2bf(b.y);
  v[6] = (short)f2bf(b.z); v[7] = (short)f2bf(b.w);
  return v;
}

// ---------------- K1: h2 = relu(edge_attr @ e1_w.T + e1_b), bf16 [E][128], via MFMA
// A[e, k] = ea (k<16), 1.0 at k==16 (bias row); B[k, c] = e1w[c, k] (k<16), e1b[c] at k==16.
__global__ __launch_bounds__(256) void k_h2(const float* __restrict__ ea,
                                            const float* __restrict__ e1w,
                                            const float* __restrict__ e1b,
                                            unsigned short* __restrict__ h2) {
  int t = threadIdx.x, w = t >> 6, l = t & 63, g = l >> 4, lm = l & 15;
  int e0 = blockIdx.x * 64 + w * 16;
  short8 bf[8];
#pragma unroll
  for (int cf = 0; cf < 8; ++cf) {
    int c = cf * 16 + lm;
    short8 v = {0, 0, 0, 0, 0, 0, 0, 0};
    if (g < 2) {
      const float4* wp = (const float4*)(e1w + c * 16 + g * 8);
      v = pack8(wp[0], wp[1]);
    } else if (g == 2) {
      v[0] = (short)f2bf(e1b[c]);
    }
    bf[cf] = v;
  }
  int er = e0 + lm; if (er >= E_) er = E_ - 1;
  short8 a = {0, 0, 0, 0, 0, 0, 0, 0};
  if (g < 2) {
    const float4* ap = (const float4*)(ea + er * 16 + g * 8);
    a = pack8(ap[0], ap[1]);
  } else if (g == 2) {
    a[0] = (short)0x3F80;  // bf16(1.0)
  }
  f32x4 z = {0.f, 0.f, 0.f, 0.f};
#pragma unroll
  for (int cf = 0; cf < 8; ++cf) {
    f32x4 acc = __builtin_amdgcn_mfma_f32_16x16x32_bf16(a, bf[cf], z, 0, 0, 0);
#pragma unroll
    for (int r = 0; r < 4; ++r) {
      int e = e0 + g * 4 + r;
      if (e < E_) h2[(size_t)e * 128 + cf * 16 + lm] = f2bf(fmaxf(acc[r], 0.f));
    }
  }
}

// ---------------- K2: pre-swizzle e2_w rows into MFMA fragment order (validated R1 layout)
// Af[((kf*256+ct)*64 + l)*8 + r] = bf16(e2w[(ct*16+(l&15))*128 + kf*32 + (l>>4)*8 + r])
__global__ __launch_bounds__(256) void k_prep_bf(const float* __restrict__ e2w,
                                                 unsigned short* __restrict__ Af) {
  int tid = blockIdx.x * 256 + threadIdx.x;  // 65536 threads
  int l = tid & 63, cf = (tid >> 6) & 255, kf = tid >> 14;
  int g = l >> 4, lm = l & 15;
  const float* src = e2w + (cf * 16 + lm) * 128 + kf * 32 + g * 8;
  float4 s0 = *(const float4*)(src);
  float4 s1 = *(const float4*)(src + 4);
  short8 v = pack8(s0, s1);
  *(short8*)((short*)Af + (size_t)tid * 8) = v;
}

// ---------------- K3: out0 = relu(nf @ mp_w.T + mp_b); y0 = out0 @ e2bmat
__global__ __launch_bounds__(256) void k_node_in(const float* __restrict__ nfm,
                                                 const float* __restrict__ mpw,
                                                 const float* __restrict__ mpb,
                                                 const float* __restrict__ e2b,
                                                 float* __restrict__ outc,
                                                 float* __restrict__ yc) {
  __shared__ float wT[64 * 65];
  __shared__ float xr[4 * 65];
  __shared__ float nr[4 * 65];
  int t = threadIdx.x;
  for (int idx = t; idx < 4096; idx += 256) {
    int o = idx >> 6, i = idx & 63;
    wT[i * 65 + o] = mpw[idx];
  }
  __syncthreads();
  int nl = t >> 6, o = t & 63;
  for (int it = 0; it < 4; ++it) {
    int n = blockIdx.x * 16 + it * 4 + nl;
    xr[nl * 65 + o] = nfm[n * 64 + o];
    __syncthreads();
    float acc = mpb[o];
#pragma unroll 8
    for (int i = 0; i < 64; ++i) acc += xr[nl * 65 + i] * wT[i * 65 + o];
    float m = fmaxf(acc, 0.f);
    outc[n * 64 + o] = m;
    nr[nl * 65 + o] = m;
    __syncthreads();
    float yv = 0.f;
#pragma unroll 8
    for (int j = 0; j < 64; ++j) yv += nr[nl * 65 + j] * e2b[j * 64 + o];
    yc[n * 64 + o] = yv;
    __syncthreads();
  }
}

// ---------------- zero kernel (once, before step 0; k_update re-zeroes thereafter)
__global__ void k_zero(float* __restrict__ p, int n) {
  int i = blockIdx.x * 256 + threadIdx.x;
  if (i < n) p[i] = 0.f;
}

// ---------------- K5: fused msgs + scatter, transposed-MFMA formulation.
// Per wave w: i in [16w,16w+16). Per (i,oq): D'[c,e] = sum_k W[c,k] h2[e,k] via
// mfma(A=W-frag, B=h2-frag); fold macc[ef][oq] += x[e,i] * D'.
__global__ __launch_bounds__(256, 3) void k_msgs(const float* __restrict__ x,
                                                 const float* __restrict__ y,
                                                 const unsigned short* __restrict__ h2,
                                                 const unsigned short* __restrict__ Af,
                                                 const int* __restrict__ ei,
                                                 float* __restrict__ agg) {
  __shared__ float xT[64 * 65];              // x transposed [i][e], padded
  __shared__ unsigned short pm[4][64 * 66];  // per-wave bf16 partial msgs
  __shared__ int sidx[64];
  __shared__ int didx[64];
  int t = threadIdx.x, w = t >> 6, l = t & 63, g = l >> 4, lm = l & 15;
  int e0 = blockIdx.x * 64;
  if (t < 64) {
    int e = e0 + t;
    sidx[t] = (e < E_) ? ei[e] : 0;
    didx[t] = (e < E_) ? ei[E_ + e] : -1;
  }
  // h2 fragments (B-operand), resident: hf[ef][kf]
  short8 hf[4][4];
#pragma unroll
  for (int ef = 0; ef < 4; ++ef) {
    int e = e0 + ef * 16 + lm;
    if (e >= E_) e = E_ - 1;
    const short8* hp = (const short8*)(h2 + (size_t)e * 128 + g * 8);
    hf[ef][0] = hp[0]; hf[ef][1] = hp[4]; hf[ef][2] = hp[8]; hf[ef][3] = hp[12];
  }
  __syncthreads();  // sidx ready
  for (int it = 0; it < 16; ++it) {
    int idx = it * 256 + t;
    int e = idx >> 6, i = idx & 63;
    xT[i * 65 + e] = x[(size_t)sidx[e] * 64 + i];
  }
  __syncthreads();  // xT ready

  f32x4 macc[4][4];  // [ef][oq]
#pragma unroll
  for (int ef = 0; ef < 4; ++ef)
#pragma unroll
    for (int oq = 0; oq < 4; ++oq) macc[ef][oq] = f32x4{0.f, 0.f, 0.f, 0.f};
  f32x4 z = {0.f, 0.f, 0.f, 0.f};
  const short8* As = (const short8*)Af;

  for (int il = 0; il < 16; ++il) {
    int i = w * 16 + il;
    float xs0 = xT[i * 65 + 0 + lm];
    float xs1 = xT[i * 65 + 16 + lm];
    float xs2 = xT[i * 65 + 32 + lm];
    float xs3 = xT[i * 65 + 48 + lm];
#pragma unroll
    for (int oq = 0; oq < 4; ++oq) {
      int ct = i * 4 + oq;
      const short8* ap = As + ct * 64 + l;
      short8 a0 = ap[0];
      short8 a1 = ap[16384];
      short8 a2 = ap[32768];
      short8 a3 = ap[49152];
      f32x4 d0, d1, d2, d3;
      d0 = __builtin_amdgcn_mfma_f32_16x16x32_bf16(a0, hf[0][0], z, 0, 0, 0);
      d1 = __builtin_amdgcn_mfma_f32_16x16x32_bf16(a0, hf[1][0], z, 0, 0, 0);
      d2 = __builtin_amdgcn_mfma_f32_16x16x32_bf16(a0, hf[2][0], z, 0, 0, 0);
      d3 = __builtin_amdgcn_mfma_f32_16x16x32_bf16(a0, hf[3][0], z, 0, 0, 0);
      d0 = __builtin_amdgcn_mfma_f32_16x16x32_bf16(a1, hf[0][1], d0, 0, 0, 0);
      d1 = __builtin_amdgcn_mfma_f32_16x16x32_bf16(a1, hf[1][1], d1, 0, 0, 0);
      d2 = __builtin_amdgcn_mfma_f32_16x16x32_bf16(a1, hf[2][1], d2, 0, 0, 0);
      d3 = __builtin_amdgcn_mfma_f32_16x16x32_bf16(a1, hf[3][1], d3, 0, 0, 0);
      d0 = __builtin_amdgcn_mfma_f32_16x16x32_bf16(a2, hf[0][2], d0, 0, 0, 0);
      d1 = __builtin_amdgcn_mfma_f32_16x16x32_bf16(a2, hf[1][2], d1, 0, 0, 0);
      d2 = __builtin_amdgcn_mfma_f32_16x16x32_bf16(a2, hf[2][2], d2, 0, 0, 0);
      d3 = __builtin_amdgcn_mfma_f32_16x16x32_bf16(a2, hf[3][2], d3, 0, 0, 0);
      d0 = __builtin_amdgcn_mfma_f32_16x16x32_bf16(a3, hf[0][3], d0, 0, 0, 0);
      d1 = __builtin_amdgcn_mfma_f32_16x16x32_bf16(a3, hf[1][3], d1, 0, 0, 0);
      d2 = __builtin_amdgcn_mfma_f32_16x16x32_bf16(a3, hf[2][3], d2, 0, 0, 0);
      d3 = __builtin_amdgcn_mfma_f32_16x16x32_bf16(a3, hf[3][3], d3, 0, 0, 0);
      macc[0][oq] += xs0 * d0;
      macc[1][oq] += xs1 * d1;
      macc[2][oq] += xs2 * d2;
      macc[3][oq] += xs3 * d3;
    }
  }
  // write per-wave partials (bf16) to LDS: e = ef*16+lm, o = oq*16+g*4+r
#pragma unroll
  for (int ef = 0; ef < 4; ++ef)
#pragma unroll
    for (int oq = 0; oq < 4; ++oq)
#pragma unroll
      for (int r = 0; r < 4; ++r) {
        int e = ef * 16 + lm, o = oq * 16 + g * 4 + r;
        pm[w][e * 66 + o] = f2bf(macc[ef][oq][r]);
      }
  __syncthreads();
  // reduce 4 waves + e2_b rank-1 term (y[src]) + scatter-add
  for (int it = 0; it < 16; ++it) {
    int idx = it * 256 + t;
    int e = idx >> 6, o = idx & 63;
    int d = didx[e];
    if (d >= 0) {
      float v = bf2f(pm[0][e * 66 + o]) + bf2f(pm[1][e * 66 + o]) +
                bf2f(pm[2][e * 66 + o]) + bf2f(pm[3][e * 66 + o]);
      v += y[(size_t)sidx[e] * 64 + o];
      atomicAdd(agg + (size_t)d * 64 + o, v);
    }
  }
}

// ---------------- K6: node update (+ re-zero agg for next step)
__global__ __launch_bounds__(256) void k_update(const float* __restrict__ outc,
                                                float* __restrict__ agg,
                                                const float* __restrict__ root,
                                                const float* __restrict__ convb,
                                                const float* __restrict__ msgw,
                                                const float* __restrict__ msgb,
                                                const float* __restrict__ e2b,
                                                const float* __restrict__ nfm,
                                                int last,
                                                float* __restrict__ outn,
                                                float* __restrict__ yn,
                                                float* __restrict__ dout) {
  __shared__ float wT[128 * 65];
  __shared__ float xr[4 * 65];
  __shared__ float mr[4 * 65];
  __shared__ float nr[4 * 65];
  int t = threadIdx.x;
  for (int idx = t; idx < 8192; idx += 256) {
    int o = idx >> 7, j = idx & 127;
    wT[j * 65 + o] = msgw[idx];
  }
  __syncthreads();
  int nl = t >> 6, o = t & 63;
  for (int it = 0; it < 4; ++it) {
    int n = blockIdx.x * 16 + it * 4 + nl;
    xr[nl * 65 + o] = outc[n * 64 + o];
    __syncthreads();
    float acc = agg[n * 64 + o] + convb[o];
    agg[n * 64 + o] = 0.f;  // re-zero for next step's scatter
#pragma unroll 8
    for (int i = 0; i < 64; ++i) acc += xr[nl * 65 + i] * root[i * 64 + o];
    float m = fmaxf(acc, 0.f);
    mr[nl * 65 + o] = m;
    __syncthreads();
    float o2 = msgb[o];
#pragma unroll 8
    for (int j = 0; j < 64; ++j)
      o2 += mr[nl * 65 + j] * wT[j * 65 + o] + xr[nl * 65 + j] * wT[(64 + j) * 65 + o];
    nr[nl * 65 + o] = o2;
    __syncthreads();
    if (last) {
      dout[n * 64 + o] = o2 + nfm[n * 64 + o];
    } else {
      float yv = 0.f;
#pragma unroll 8
      for (int j = 0; j < 64; ++j) yv += nr[nl * 65 + j] * e2b[j * 64 + o];
      outn[n * 64 + o] = o2;
      yn[n * 64 + o] = yv;
    }
    __syncthreads();
  }
}

extern "C" void kernel_launch(void* const* d_in, const int* in_sizes, int n_in,
                              void* d_out, int out_size, void* d_ws, size_t ws_size,
                              hipStream_t stream) {
  const float* nfm  = (const float*)d_in[0];
  const float* ea   = (const float*)d_in[1];
  const int*   ei   = (const int*)d_in[2];
  const float* mpw  = (const float*)d_in[3];
  const float* mpb  = (const float*)d_in[4];
  const float* msgw = (const float*)d_in[5];
  const float* msgb = (const float*)d_in[6];
  const float* e1w  = (const float*)d_in[7];
  const float* e1b  = (const float*)d_in[8];
  const float* e2w  = (const float*)d_in[9];
  const float* e2b  = (const float*)d_in[10];
  const float* root = (const float*)d_in[11];
  const float* convb= (const float*)d_in[12];
  float* out = (float*)d_out;

  char* ws = (char*)d_ws;
  unsigned short* h2 = (unsigned short*)ws; ws += (size_t)E_ * 128 * 2;
  unsigned short* Af = (unsigned short*)ws; ws += (size_t)4096 * 128 * 2;
  float* outa = (float*)ws; ws += (size_t)N_ * 64 * 4;
  float* ya   = (float*)ws; ws += (size_t)N_ * 64 * 4;
  float* outb = (float*)ws; ws += (size_t)N_ * 64 * 4;
  float* yb   = (float*)ws; ws += (size_t)N_ * 64 * 4;
  float* agg  = (float*)ws; ws += (size_t)N_ * 64 * 4;

  hipLaunchKernelGGL(k_prep_bf, dim3(256), dim3(256), 0, stream, e2w, Af);
  hipLaunchKernelGGL(k_zero, dim3((N_ * 64 + 255) / 256), dim3(256), 0, stream, agg, N_ * 64);
  hipLaunchKernelGGL(k_h2, dim3((E_ + 63) / 64), dim3(256), 0, stream, ea, e1w, e1b, h2);
  hipLaunchKernelGGL(k_node_in, dim3(N_ / 16), dim3(256), 0, stream, nfm, mpw, mpb, e2b, outa, ya);

  float* oc = outa; float* yc = ya; float* on = outb; float* yv = yb;
  for (int s = 0; s < 3; ++s) {
    hipLaunchKernelGGL(k_msgs, dim3((E_ + 63) / 64), dim3(256), 0, stream, oc, yc, h2, Af, ei, agg);
    hipLaunchKernelGGL(k_update, dim3(N_ / 16), dim3(256), 0, stream, oc, agg, root, convb,
                       msgw, msgb, e2b, nfm, (s == 2) ? 1 : 0, on, yv, out);
    float* tp;
    tp = oc; oc = on; on = tp;
    tp = yc; yc = yv; yv = tp;
  }
}

// Round 3
// 764.366 us; speedup vs baseline: 1.1989x; 1.1989x over previous
//
#include <hip/hip_runtime.h>

#define N_ 20000
#define E_ 100000

typedef __attribute__((ext_vector_type(8))) short short8;
typedef __attribute__((ext_vector_type(4))) float f32x4;

__device__ __forceinline__ unsigned short f2bf(float f) {
  union { float f; unsigned u; } v; v.f = f;
  unsigned r = v.u + 0x7fffu + ((v.u >> 16) & 1u);
  return (unsigned short)(r >> 16);
}
__device__ __forceinline__ float bf2f(unsigned short h) {
  union { unsigned u; float f; } v; v.u = ((unsigned)h) << 16;
  return v.f;
}
__device__ __forceinline__ short8 pack8(float4 a, float4 b) {
  short8 v;
  v[0] = (short)f2bf(a.x); v[1] = (short)f2bf(a.y);
  v[2] = (short)f2bf(a.z); v[3] = (short)f2bf(a.w);
  v[4] = (short)f2bf(b.x); v[5] = (short)f2bf(b.y);
  v[6] = (short)f2bf(b.z); v[7] = (short)f2bf(b.w);
  return v;
}
__device__ __forceinline__ void glds16(const unsigned short* g, unsigned char* lds) {
  __builtin_amdgcn_global_load_lds(
      (const __attribute__((address_space(1))) unsigned int*)g,
      (__attribute__((address_space(3))) unsigned int*)lds, 16, 0, 0);
}

// ---------------- K1: h2 = relu(edge_attr @ e1_w.T + e1_b), bf16 [E][128], via MFMA
__global__ __launch_bounds__(256) void k_h2(const float* __restrict__ ea,
                                            const float* __restrict__ e1w,
                                            const float* __restrict__ e1b,
                                            unsigned short* __restrict__ h2) {
  int t = threadIdx.x, w = t >> 6, l = t & 63, g = l >> 4, lm = l & 15;
  int e0 = blockIdx.x * 64 + w * 16;
  short8 bf[8];
#pragma unroll
  for (int cf = 0; cf < 8; ++cf) {
    int c = cf * 16 + lm;
    short8 v = {0, 0, 0, 0, 0, 0, 0, 0};
    if (g < 2) {
      const float4* wp = (const float4*)(e1w + c * 16 + g * 8);
      v = pack8(wp[0], wp[1]);
    } else if (g == 2) {
      v[0] = (short)f2bf(e1b[c]);
    }
    bf[cf] = v;
  }
  int er = e0 + lm; if (er >= E_) er = E_ - 1;
  short8 a = {0, 0, 0, 0, 0, 0, 0, 0};
  if (g < 2) {
    const float4* ap = (const float4*)(ea + er * 16 + g * 8);
    a = pack8(ap[0], ap[1]);
  } else if (g == 2) {
    a[0] = (short)0x3F80;  // bf16(1.0)
  }
  f32x4 z = {0.f, 0.f, 0.f, 0.f};
#pragma unroll
  for (int cf = 0; cf < 8; ++cf) {
    f32x4 acc = __builtin_amdgcn_mfma_f32_16x16x32_bf16(a, bf[cf], z, 0, 0, 0);
#pragma unroll
    for (int r = 0; r < 4; ++r) {
      int e = e0 + g * 4 + r;
      if (e < E_) h2[(size_t)e * 128 + cf * 16 + lm] = f2bf(fmaxf(acc[r], 0.f));
    }
  }
}

// ---------------- K2: pre-swizzle e2_w into chunk-contiguous MFMA A-frag order
// Af[((ct*4 + kf)*64 + l)*8 + r] = bf16(e2w[(ct*16+(l&15))*128 + kf*32 + (l>>4)*8 + r])
__global__ __launch_bounds__(256) void k_prep_bf(const float* __restrict__ e2w,
                                                 unsigned short* __restrict__ Af) {
  int tid = blockIdx.x * 256 + threadIdx.x;  // 65536 threads
  int l = tid & 63, kf = (tid >> 6) & 3, ct = tid >> 8;
  int gq = l >> 4, lm = l & 15;
  const float* src = e2w + (ct * 16 + lm) * 128 + kf * 32 + gq * 8;
  short8 v = pack8(*(const float4*)src, *(const float4*)(src + 4));
  *(short8*)((short*)Af + (size_t)tid * 8) = v;
}

// ---------------- K3: out0 = relu(nf @ mp_w.T + mp_b); y0 = out0 @ e2bmat
__global__ __launch_bounds__(256) void k_node_in(const float* __restrict__ nfm,
                                                 const float* __restrict__ mpw,
                                                 const float* __restrict__ mpb,
                                                 const float* __restrict__ e2b,
                                                 float* __restrict__ outc,
                                                 float* __restrict__ yc) {
  __shared__ float wT[64 * 65];
  __shared__ float xr[4 * 65];
  __shared__ float nr[4 * 65];
  int t = threadIdx.x;
  for (int idx = t; idx < 4096; idx += 256) {
    int o = idx >> 6, i = idx & 63;
    wT[i * 65 + o] = mpw[idx];
  }
  __syncthreads();
  int nl = t >> 6, o = t & 63;
  for (int it = 0; it < 4; ++it) {
    int n = blockIdx.x * 16 + it * 4 + nl;
    xr[nl * 65 + o] = nfm[n * 64 + o];
    __syncthreads();
    float acc = mpb[o];
#pragma unroll 8
    for (int i = 0; i < 64; ++i) acc += xr[nl * 65 + i] * wT[i * 65 + o];
    float m = fmaxf(acc, 0.f);
    outc[n * 64 + o] = m;
    nr[nl * 65 + o] = m;
    __syncthreads();
    float yv = 0.f;
#pragma unroll 8
    for (int j = 0; j < 64; ++j) yv += nr[nl * 65 + j] * e2b[j * 64 + o];
    yc[n * 64 + o] = yv;
    __syncthreads();
  }
}

// ---------------- zero kernel (once; k_update re-zeroes thereafter)
__global__ void k_zero(float* __restrict__ p, int n) {
  int i = blockIdx.x * 256 + threadIdx.x;
  if (i < n) p[i] = 0.f;
}

// ---------------- K5: fused msgs + scatter. 128 edges/block, 4 waves.
// wave w: s=w>>1 (i-range s*32..s*32+32), g=w&1 (edge half g*64..g*64+64).
// W-frags staged L2->LDS via global_load_lds, triple-buffered per s-pair,
// counted vmcnt(2) + raw s_barrier (no drain in loop).
__global__ __launch_bounds__(256, 2) void k_msgs(const float* __restrict__ x,
                                                 const float* __restrict__ y,
                                                 const unsigned short* __restrict__ h2,
                                                 const unsigned short* __restrict__ Af,
                                                 const int* __restrict__ ei,
                                                 float* __restrict__ agg) {
  __shared__ __align__(16) unsigned char POOL[40960];  // [0,24576) Wbuf 2 pairs x3x4KB; [24576,40960) xg
  __shared__ int sidx[128];
  __shared__ int didx[128];
  int t = threadIdx.x, w = t >> 6, l = t & 63;
  int g = w & 1, s = w >> 1;
  int gq = l >> 4, lm = l & 15;
  int e0 = blockIdx.x * 128;
  if (t < 128) {
    int e = e0 + t;
    sidx[t] = (e < E_) ? ei[e] : 0;
    didx[t] = (e < E_) ? ei[E_ + e] : -1;
  }
  __syncthreads();  // sidx ready
  // h2 fragments (B-operand) for wave's 64 edges: af[ef][kf]
  short8 af[4][4];
#pragma unroll
  for (int ef = 0; ef < 4; ++ef) {
    int e = e0 + g * 64 + ef * 16 + lm;
    if (e >= E_) e = E_ - 1;
    const short8* hp = (const short8*)(h2 + (size_t)e * 128 + gq * 8);
    af[ef][0] = hp[0]; af[ef][1] = hp[4]; af[ef][2] = hp[8]; af[ef][3] = hp[12];
  }
  // xg gather: bf16 [i 0..63][e 0..127]
  unsigned short* xg = (unsigned short*)(POOL + 24576);
  {
    int e = t >> 1, hh = t & 1;
    const float* xr = x + (size_t)sidx[e] * 64 + hh * 32;
#pragma unroll
    for (int q = 0; q < 8; ++q) {
      float4 v = *(const float4*)(xr + q * 4);
      int i = hh * 32 + q * 4;
      xg[(i + 0) * 128 + e] = f2bf(v.x);
      xg[(i + 1) * 128 + e] = f2bf(v.y);
      xg[(i + 2) * 128 + e] = f2bf(v.z);
      xg[(i + 3) * 128 + e] = f2bf(v.w);
    }
  }
  asm volatile("s_waitcnt vmcnt(0)" ::: "memory");  // af+x loads done; vm counter clean
  __syncthreads();  // xg ready

  unsigned char* Pbase = POOL + s * 12288;
  f32x4 macc[4][4];
#pragma unroll
  for (int ef = 0; ef < 4; ++ef)
#pragma unroll
    for (int oq = 0; oq < 4; ++oq) macc[ef][oq] = f32x4{0.f, 0.f, 0.f, 0.f};
  const f32x4 z = {0.f, 0.f, 0.f, 0.f};
  int kf0 = g * 2;

  // stage chunk tc (wave stages its 2 kf-frags of the 4KB chunk)
#define STAGE(tc)                                                              \
  {                                                                            \
    int dc = (tc) & 127, buf = (tc) % 3;                                       \
    int dct = (s * 32 + (dc >> 2)) * 4 + (dc & 3);                             \
    glds16(Af + ((size_t)(dct * 4 + kf0) * 64 + l) * 8,                        \
           Pbase + buf * 4096 + kf0 * 1024);                                   \
    glds16(Af + ((size_t)(dct * 4 + kf0 + 1) * 64 + l) * 8,                    \
           Pbase + buf * 4096 + (kf0 + 1) * 1024);                             \
  }

  STAGE(0);
  STAGE(1);
  int c = 0;
  for (int il = 0; il < 32; ++il) {
    int ib = s * 32 + il;
    float xs0 = bf2f(xg[ib * 128 + g * 64 + 0 + lm]);
    float xs1 = bf2f(xg[ib * 128 + g * 64 + 16 + lm]);
    float xs2 = bf2f(xg[ib * 128 + g * 64 + 32 + lm]);
    float xs3 = bf2f(xg[ib * 128 + g * 64 + 48 + lm]);
#pragma unroll
    for (int oq = 0; oq < 4; ++oq, ++c) {
      asm volatile("s_waitcnt vmcnt(2)" ::: "memory");  // chunk c landed (mine)
      __builtin_amdgcn_s_barrier();                     // partner's too
      STAGE(c + 2);                                     // into buf (c+2)%3 (free)
      const unsigned short* Wb = (const unsigned short*)(Pbase + (c % 3) * 4096);
      short8 wf0 = *(const short8*)(Wb + 0 + l * 8);
      short8 wf1 = *(const short8*)(Wb + 512 + l * 8);
      short8 wf2 = *(const short8*)(Wb + 1024 + l * 8);
      short8 wf3 = *(const short8*)(Wb + 1536 + l * 8);
      f32x4 d0, d1, d2, d3;
      d0 = __builtin_amdgcn_mfma_f32_16x16x32_bf16(wf0, af[0][0], z, 0, 0, 0);
      d1 = __builtin_amdgcn_mfma_f32_16x16x32_bf16(wf0, af[1][0], z, 0, 0, 0);
      d2 = __builtin_amdgcn_mfma_f32_16x16x32_bf16(wf0, af[2][0], z, 0, 0, 0);
      d3 = __builtin_amdgcn_mfma_f32_16x16x32_bf16(wf0, af[3][0], z, 0, 0, 0);
      d0 = __builtin_amdgcn_mfma_f32_16x16x32_bf16(wf1, af[0][1], d0, 0, 0, 0);
      d1 = __builtin_amdgcn_mfma_f32_16x16x32_bf16(wf1, af[1][1], d1, 0, 0, 0);
      d2 = __builtin_amdgcn_mfma_f32_16x16x32_bf16(wf1, af[2][1], d2, 0, 0, 0);
      d3 = __builtin_amdgcn_mfma_f32_16x16x32_bf16(wf1, af[3][1], d3, 0, 0, 0);
      d0 = __builtin_amdgcn_mfma_f32_16x16x32_bf16(wf2, af[0][2], d0, 0, 0, 0);
      d1 = __builtin_amdgcn_mfma_f32_16x16x32_bf16(wf2, af[1][2], d1, 0, 0, 0);
      d2 = __builtin_amdgcn_mfma_f32_16x16x32_bf16(wf2, af[2][2], d2, 0, 0, 0);
      d3 = __builtin_amdgcn_mfma_f32_16x16x32_bf16(wf2, af[3][2], d3, 0, 0, 0);
      d0 = __builtin_amdgcn_mfma_f32_16x16x32_bf16(wf3, af[0][3], d0, 0, 0, 0);
      d1 = __builtin_amdgcn_mfma_f32_16x16x32_bf16(wf3, af[1][3], d1, 0, 0, 0);
      d2 = __builtin_amdgcn_mfma_f32_16x16x32_bf16(wf3, af[2][3], d2, 0, 0, 0);
      d3 = __builtin_amdgcn_mfma_f32_16x16x32_bf16(wf3, af[3][3], d3, 0, 0, 0);
      macc[0][oq] += xs0 * d0;
      macc[1][oq] += xs1 * d1;
      macc[2][oq] += xs2 * d2;
      macc[3][oq] += xs3 * d3;
    }
  }
#undef STAGE
  asm volatile("s_waitcnt vmcnt(0)" ::: "memory");  // drain wrapped stages
  __syncthreads();
  // partial msgs (bf16) -> POOL (Wbuf/xg dead); slice w at w*4224 shorts
  unsigned short* pm = (unsigned short*)POOL;
  unsigned short* pw = pm + w * 4224;
#pragma unroll
  for (int ef = 0; ef < 4; ++ef)
#pragma unroll
    for (int oq = 0; oq < 4; ++oq)
#pragma unroll
      for (int r = 0; r < 4; ++r)
        pw[(ef * 16 + lm) * 66 + oq * 16 + gq * 4 + r] = f2bf(macc[ef][oq][r]);
  __syncthreads();
  // reduce i-split pairs + e2_b rank-1 term (y[src]) + scatter-add
  for (int it = 0; it < 32; ++it) {
    int idx = it * 256 + t;
    int e = idx >> 6, o = idx & 63;
    int d = didx[e];
    if (d >= 0) {
      int gg = e >> 6, eh = e & 63;
      float v = bf2f(pm[gg * 4224 + eh * 66 + o]) + bf2f(pm[(2 + gg) * 4224 + eh * 66 + o]);
      v += y[(size_t)sidx[e] * 64 + o];
      atomicAdd(agg + (size_t)d * 64 + o, v);
    }
  }
}

// ---------------- K6: node update (+ re-zero agg for next step)
__global__ __launch_bounds__(256) void k_update(const float* __restrict__ outc,
                                                float* __restrict__ agg,
                                                const float* __restrict__ root,
                                                const float* __restrict__ convb,
                                                const float* __restrict__ msgw,
                                                const float* __restrict__ msgb,
                                                const float* __restrict__ e2b,
                                                const float* __restrict__ nfm,
                                                int last,
                                                float* __restrict__ outn,
                                                float* __restrict__ yn,
                                                float* __restrict__ dout) {
  __shared__ float wT[128 * 65];
  __shared__ float xr[4 * 65];
  __shared__ float mr[4 * 65];
  __shared__ float nr[4 * 65];
  int t = threadIdx.x;
  for (int idx = t; idx < 8192; idx += 256) {
    int o = idx >> 7, j = idx & 127;
    wT[j * 65 + o] = msgw[idx];
  }
  __syncthreads();
  int nl = t >> 6, o = t & 63;
  for (int it = 0; it < 4; ++it) {
    int n = blockIdx.x * 16 + it * 4 + nl;
    xr[nl * 65 + o] = outc[n * 64 + o];
    __syncthreads();
    float acc = agg[n * 64 + o] + convb[o];
    agg[n * 64 + o] = 0.f;
#pragma unroll 8
    for (int i = 0; i < 64; ++i) acc += xr[nl * 65 + i] * root[i * 64 + o];
    float m = fmaxf(acc, 0.f);
    mr[nl * 65 + o] = m;
    __syncthreads();
    float o2 = msgb[o];
#pragma unroll 8
    for (int j = 0; j < 64; ++j)
      o2 += mr[nl * 65 + j] * wT[j * 65 + o] + xr[nl * 65 + j] * wT[(64 + j) * 65 + o];
    nr[nl * 65 + o] = o2;
    __syncthreads();
    if (last) {
      dout[n * 64 + o] = o2 + nfm[n * 64 + o];
    } else {
      float yv = 0.f;
#pragma unroll 8
      for (int j = 0; j < 64; ++j) yv += nr[nl * 65 + j] * e2b[j * 64 + o];
      outn[n * 64 + o] = o2;
      yn[n * 64 + o] = yv;
    }
    __syncthreads();
  }
}

extern "C" void kernel_launch(void* const* d_in, const int* in_sizes, int n_in,
                              void* d_out, int out_size, void* d_ws, size_t ws_size,
                              hipStream_t stream) {
  const float* nfm  = (const float*)d_in[0];
  const float* ea   = (const float*)d_in[1];
  const int*   ei   = (const int*)d_in[2];
  const float* mpw  = (const float*)d_in[3];
  const float* mpb  = (const float*)d_in[4];
  const float* msgw = (const float*)d_in[5];
  const float* msgb = (const float*)d_in[6];
  const float* e1w  = (const float*)d_in[7];
  const float* e1b  = (const float*)d_in[8];
  const float* e2w  = (const float*)d_in[9];
  const float* e2b  = (const float*)d_in[10];
  const float* root = (const float*)d_in[11];
  const float* convb= (const float*)d_in[12];
  float* out = (float*)d_out;

  char* ws = (char*)d_ws;
  unsigned short* h2 = (unsigned short*)ws; ws += (size_t)E_ * 128 * 2;
  unsigned short* Af = (unsigned short*)ws; ws += (size_t)4096 * 128 * 2;
  float* outa = (float*)ws; ws += (size_t)N_ * 64 * 4;
  float* ya   = (float*)ws; ws += (size_t)N_ * 64 * 4;
  float* outb = (float*)ws; ws += (size_t)N_ * 64 * 4;
  float* yb   = (float*)ws; ws += (size_t)N_ * 64 * 4;
  float* agg  = (float*)ws; ws += (size_t)N_ * 64 * 4;

  hipLaunchKernelGGL(k_prep_bf, dim3(256), dim3(256), 0, stream, e2w, Af);
  hipLaunchKernelGGL(k_zero, dim3((N_ * 64 + 255) / 256), dim3(256), 0, stream, agg, N_ * 64);
  hipLaunchKernelGGL(k_h2, dim3((E_ + 63) / 64), dim3(256), 0, stream, ea, e1w, e1b, h2);
  hipLaunchKernelGGL(k_node_in, dim3(N_ / 16), dim3(256), 0, stream, nfm, mpw, mpb, e2b, outa, ya);

  float* oc = outa; float* yc = ya; float* on = outb; float* yv = yb;
  for (int s = 0; s < 3; ++s) {
    hipLaunchKernelGGL(k_msgs, dim3((E_ + 127) / 128), dim3(256), 0, stream, oc, yc, h2, Af, ei, agg);
    hipLaunchKernelGGL(k_update, dim3(N_ / 16), dim3(256), 0, stream, oc, agg, root, convb,
                       msgw, msgb, e2b, nfm, (s == 2) ? 1 : 0, on, yv, out);
    float* tp;
    tp = oc; oc = on; on = tp;
    tp = yc; yc = yv; yv = tp;
  }
}

// Round 4
// 694.168 us; speedup vs baseline: 1.3202x; 1.1011x over previous
//
#include <hip/hip_runtime.h>

#define N_ 20000
#define E_ 100000

typedef __attribute__((ext_vector_type(8))) short short8;
typedef __attribute__((ext_vector_type(4))) float f32x4;

__device__ __forceinline__ unsigned short f2bf(float f) {
  union { float f; unsigned u; } v; v.f = f;
  unsigned r = v.u + 0x7fffu + ((v.u >> 16) & 1u);
  return (unsigned short)(r >> 16);
}
__device__ __forceinline__ float bf2f(unsigned short h) {
  union { unsigned u; float f; } v; v.u = ((unsigned)h) << 16;
  return v.f;
}
__device__ __forceinline__ short8 pack8(float4 a, float4 b) {
  short8 v;
  v[0] = (short)f2bf(a.x); v[1] = (short)f2bf(a.y);
  v[2] = (short)f2bf(a.z); v[3] = (short)f2bf(a.w);
  v[4] = (short)f2bf(b.x); v[5] = (short)f2bf(b.y);
  v[6] = (short)f2bf(b.z); v[7] = (short)f2bf(b.w);
  return v;
}

// ---------------- K1: h2 = relu(edge_attr @ e1_w.T + e1_b), bf16 [E][128], via MFMA
// 256 edges/block: 4 waves x 4 tiles of 16 edges; e1w frags loaded once per wave.
__global__ __launch_bounds__(256) void k_h2(const float* __restrict__ ea,
                                            const float* __restrict__ e1w,
                                            const float* __restrict__ e1b,
                                            unsigned short* __restrict__ h2) {
  int t = threadIdx.x, w = t >> 6, l = t & 63, g = l >> 4, lm = l & 15;
  short8 bf[8];
#pragma unroll
  for (int cf = 0; cf < 8; ++cf) {
    int c = cf * 16 + lm;
    short8 v = {0, 0, 0, 0, 0, 0, 0, 0};
    if (g < 2) {
      const float4* wp = (const float4*)(e1w + c * 16 + g * 8);
      v = pack8(wp[0], wp[1]);
    } else if (g == 2) {
      v[0] = (short)f2bf(e1b[c]);
    }
    bf[cf] = v;
  }
  const f32x4 z = {0.f, 0.f, 0.f, 0.f};
  for (int tile = 0; tile < 4; ++tile) {
    int e0 = blockIdx.x * 256 + tile * 64 + w * 16;
    if (e0 >= E_) break;
    int er = e0 + lm; if (er >= E_) er = E_ - 1;
    short8 a = {0, 0, 0, 0, 0, 0, 0, 0};
    if (g < 2) {
      const float4* ap = (const float4*)(ea + er * 16 + g * 8);
      a = pack8(ap[0], ap[1]);
    } else if (g == 2) {
      a[0] = (short)0x3F80;  // bf16(1.0)
    }
#pragma unroll
    for (int cf = 0; cf < 8; ++cf) {
      f32x4 acc = __builtin_amdgcn_mfma_f32_16x16x32_bf16(a, bf[cf], z, 0, 0, 0);
#pragma unroll
      for (int r = 0; r < 4; ++r) {
        int e = e0 + g * 4 + r;
        if (e < E_) h2[(size_t)e * 128 + cf * 16 + lm] = f2bf(fmaxf(acc[r], 0.f));
      }
    }
  }
}

// ---------------- K2: pre-swizzle e2_w into chunk-contiguous MFMA A-frag order
// Af[((ct*4 + kf)*64 + l)*8 + r] = bf16(e2w[(ct*16+(l&15))*128 + kf*32 + (l>>4)*8 + r])
__global__ __launch_bounds__(256) void k_prep_bf(const float* __restrict__ e2w,
                                                 unsigned short* __restrict__ Af) {
  int tid = blockIdx.x * 256 + threadIdx.x;  // 65536 threads
  int l = tid & 63, kf = (tid >> 6) & 3, ct = tid >> 8;
  int gq = l >> 4, lm = l & 15;
  const float* src = e2w + (ct * 16 + lm) * 128 + kf * 32 + gq * 8;
  short8 v = pack8(*(const float4*)src, *(const float4*)(src + 4));
  *(short8*)((short*)Af + (size_t)tid * 8) = v;
}

// ---------------- K3: out0 = relu(nf @ mp_w.T + mp_b); y0 = out0 @ e2bmat
__global__ __launch_bounds__(256) void k_node_in(const float* __restrict__ nfm,
                                                 const float* __restrict__ mpw,
                                                 const float* __restrict__ mpb,
                                                 const float* __restrict__ e2b,
                                                 float* __restrict__ outc,
                                                 float* __restrict__ yc) {
  __shared__ float wT[64 * 65];
  __shared__ float xr[4 * 65];
  __shared__ float nr[4 * 65];
  int t = threadIdx.x;
  for (int idx = t; idx < 4096; idx += 256) {
    int o = idx >> 6, i = idx & 63;
    wT[i * 65 + o] = mpw[idx];
  }
  __syncthreads();
  int nl = t >> 6, o = t & 63;
  for (int it = 0; it < 4; ++it) {
    int n = blockIdx.x * 16 + it * 4 + nl;
    xr[nl * 65 + o] = nfm[n * 64 + o];
    __syncthreads();
    float acc = mpb[o];
#pragma unroll 8
    for (int i = 0; i < 64; ++i) acc += xr[nl * 65 + i] * wT[i * 65 + o];
    float m = fmaxf(acc, 0.f);
    outc[n * 64 + o] = m;
    nr[nl * 65 + o] = m;
    __syncthreads();
    float yv = 0.f;
#pragma unroll 8
    for (int j = 0; j < 64; ++j) yv += nr[nl * 65 + j] * e2b[j * 64 + o];
    yc[n * 64 + o] = yv;
    __syncthreads();
  }
}

// ---------------- zero kernel (once; k_update re-zeroes thereafter)
__global__ void k_zero(float* __restrict__ p, int n) {
  int i = blockIdx.x * 256 + threadIdx.x;
  if (i < n) p[i] = 0.f;
}

// ---------------- K5: fused msgs + scatter. 128 edges/block, 512 threads, 8 waves.
// wave w: s=w>>2 (i-half: 32 i's), q=w&3 (edge quarter: 32 edges).
// W-frags loaded direct L2->reg (no barriers in loop; q-waves' duplicate reads L1-hit).
__global__ __launch_bounds__(512, 4) void k_msgs(const float* __restrict__ x,
                                                 const float* __restrict__ y,
                                                 const unsigned short* __restrict__ h2,
                                                 const unsigned short* __restrict__ Af,
                                                 const int* __restrict__ ei,
                                                 float* __restrict__ agg) {
  __shared__ unsigned short xg[64 * 130];     // bf16 x^T [i][e] padded
  __shared__ unsigned short pm[8 * 32 * 66];  // per-wave bf16 partials
  __shared__ int sidx[128];
  __shared__ int didx[128];
  int t = threadIdx.x, w = t >> 6, l = t & 63;
  int s = w >> 2, q = w & 3;
  int gq = l >> 4, lm = l & 15;
  int e0 = blockIdx.x * 128;
  if (t < 128) {
    int e = e0 + t;
    sidx[t] = (e < E_) ? ei[e] : 0;
    didx[t] = (e < E_) ? ei[E_ + e] : -1;
  }
  __syncthreads();  // sidx ready
  // h2 fragments (B-operand) for wave's 32 edges: hf[ef][kf]
  short8 hf[2][4];
#pragma unroll
  for (int ef = 0; ef < 2; ++ef) {
    int e = e0 + q * 32 + ef * 16 + lm;
    if (e >= E_) e = E_ - 1;
    const short8* hp = (const short8*)(h2 + (size_t)e * 128 + gq * 8);
    hf[ef][0] = hp[0]; hf[ef][1] = hp[4]; hf[ef][2] = hp[8]; hf[ef][3] = hp[12];
  }
  // xg gather: bf16 [i][e]; thread covers edge t>>2, i-segment (t&3)*16
  {
    int e = t >> 2, seg = t & 3;
    const float* xr = x + (size_t)sidx[e] * 64 + seg * 16;
    float4 v0 = *(const float4*)(xr + 0);
    float4 v1 = *(const float4*)(xr + 4);
    float4 v2 = *(const float4*)(xr + 8);
    float4 v3 = *(const float4*)(xr + 12);
    int ib = seg * 16;
    xg[(ib + 0) * 130 + e] = f2bf(v0.x);  xg[(ib + 1) * 130 + e] = f2bf(v0.y);
    xg[(ib + 2) * 130 + e] = f2bf(v0.z);  xg[(ib + 3) * 130 + e] = f2bf(v0.w);
    xg[(ib + 4) * 130 + e] = f2bf(v1.x);  xg[(ib + 5) * 130 + e] = f2bf(v1.y);
    xg[(ib + 6) * 130 + e] = f2bf(v1.z);  xg[(ib + 7) * 130 + e] = f2bf(v1.w);
    xg[(ib + 8) * 130 + e] = f2bf(v2.x);  xg[(ib + 9) * 130 + e] = f2bf(v2.y);
    xg[(ib + 10) * 130 + e] = f2bf(v2.z); xg[(ib + 11) * 130 + e] = f2bf(v2.w);
    xg[(ib + 12) * 130 + e] = f2bf(v3.x); xg[(ib + 13) * 130 + e] = f2bf(v3.y);
    xg[(ib + 14) * 130 + e] = f2bf(v3.z); xg[(ib + 15) * 130 + e] = f2bf(v3.w);
  }
  __syncthreads();  // xg ready

  f32x4 macc[2][4];  // [ef][oq]
#pragma unroll
  for (int ef = 0; ef < 2; ++ef)
#pragma unroll
    for (int oq = 0; oq < 4; ++oq) macc[ef][oq] = f32x4{0.f, 0.f, 0.f, 0.f};
  const f32x4 z = {0.f, 0.f, 0.f, 0.f};
  const short8* As = (const short8*)Af;

  for (int il = 0; il < 32; ++il) {
    int i = s * 32 + il;
    float xs0 = bf2f(xg[i * 130 + q * 32 + lm]);
    float xs1 = bf2f(xg[i * 130 + q * 32 + 16 + lm]);
#pragma unroll
    for (int oq = 0; oq < 4; ++oq) {
      int ct = i * 4 + oq;
      const short8* ap = As + (size_t)ct * 256 + l;
      short8 a0 = ap[0];
      short8 a1 = ap[64];
      short8 a2 = ap[128];
      short8 a3 = ap[192];
      f32x4 d0, d1;
      d0 = __builtin_amdgcn_mfma_f32_16x16x32_bf16(a0, hf[0][0], z, 0, 0, 0);
      d1 = __builtin_amdgcn_mfma_f32_16x16x32_bf16(a0, hf[1][0], z, 0, 0, 0);
      d0 = __builtin_amdgcn_mfma_f32_16x16x32_bf16(a1, hf[0][1], d0, 0, 0, 0);
      d1 = __builtin_amdgcn_mfma_f32_16x16x32_bf16(a1, hf[1][1], d1, 0, 0, 0);
      d0 = __builtin_amdgcn_mfma_f32_16x16x32_bf16(a2, hf[0][2], d0, 0, 0, 0);
      d1 = __builtin_amdgcn_mfma_f32_16x16x32_bf16(a2, hf[1][2], d1, 0, 0, 0);
      d0 = __builtin_amdgcn_mfma_f32_16x16x32_bf16(a3, hf[0][3], d0, 0, 0, 0);
      d1 = __builtin_amdgcn_mfma_f32_16x16x32_bf16(a3, hf[1][3], d1, 0, 0, 0);
      macc[0][oq] += xs0 * d0;
      macc[1][oq] += xs1 * d1;
    }
  }
  // per-wave partials -> LDS: e_local = ef*16+lm (0..31), o = oq*16+gq*4+r
  unsigned short* pw = pm + w * 2112;
#pragma unroll
  for (int ef = 0; ef < 2; ++ef)
#pragma unroll
    for (int oq = 0; oq < 4; ++oq)
#pragma unroll
      for (int r = 0; r < 4; ++r)
        pw[(ef * 16 + lm) * 66 + oq * 16 + gq * 4 + r] = f2bf(macc[ef][oq][r]);
  __syncthreads();
  // reduce s-pairs + e2_b rank-1 term (y[src]) + scatter-add
  for (int it = 0; it < 16; ++it) {
    int idx = it * 512 + t;
    int e = idx >> 6, o = idx & 63;
    int d = didx[e];
    if (d >= 0) {
      int qe = e >> 5, el = e & 31;
      float v = bf2f(pm[qe * 2112 + el * 66 + o]) + bf2f(pm[(4 + qe) * 2112 + el * 66 + o]);
      v += y[(size_t)sidx[e] * 64 + o];
      atomicAdd(agg + (size_t)d * 64 + o, v);
    }
  }
}

// ---------------- K6: node update (+ re-zero agg for next step)
__global__ __launch_bounds__(256) void k_update(const float* __restrict__ outc,
                                                float* __restrict__ agg,
                                                const float* __restrict__ root,
                                                const float* __restrict__ convb,
                                                const float* __restrict__ msgw,
                                                const float* __restrict__ msgb,
                                                const float* __restrict__ e2b,
                                                const float* __restrict__ nfm,
                                                int last,
                                                float* __restrict__ outn,
                                                float* __restrict__ yn,
                                                float* __restrict__ dout) {
  __shared__ float wT[128 * 65];
  __shared__ float xr[4 * 65];
  __shared__ float mr[4 * 65];
  __shared__ float nr[4 * 65];
  int t = threadIdx.x;
  for (int idx = t; idx < 8192; idx += 256) {
    int o = idx >> 7, j = idx & 127;
    wT[j * 65 + o] = msgw[idx];
  }
  __syncthreads();
  int nl = t >> 6, o = t & 63;
  for (int it = 0; it < 4; ++it) {
    int n = blockIdx.x * 16 + it * 4 + nl;
    xr[nl * 65 + o] = outc[n * 64 + o];
    __syncthreads();
    float acc = agg[n * 64 + o] + convb[o];
    agg[n * 64 + o] = 0.f;
#pragma unroll 8
    for (int i = 0; i < 64; ++i) acc += xr[nl * 65 + i] * root[i * 64 + o];
    float m = fmaxf(acc, 0.f);
    mr[nl * 65 + o] = m;
    __syncthreads();
    float o2 = msgb[o];
#pragma unroll 8
    for (int j = 0; j < 64; ++j)
      o2 += mr[nl * 65 + j] * wT[j * 65 + o] + xr[nl * 65 + j] * wT[(64 + j) * 65 + o];
    nr[nl * 65 + o] = o2;
    __syncthreads();
    if (last) {
      dout[n * 64 + o] = o2 + nfm[n * 64 + o];
    } else {
      float yv = 0.f;
#pragma unroll 8
      for (int j = 0; j < 64; ++j) yv += nr[nl * 65 + j] * e2b[j * 64 + o];
      outn[n * 64 + o] = o2;
      yn[n * 64 + o] = yv;
    }
    __syncthreads();
  }
}

extern "C" void kernel_launch(void* const* d_in, const int* in_sizes, int n_in,
                              void* d_out, int out_size, void* d_ws, size_t ws_size,
                              hipStream_t stream) {
  const float* nfm  = (const float*)d_in[0];
  const float* ea   = (const float*)d_in[1];
  const int*   ei   = (const int*)d_in[2];
  const float* mpw  = (const float*)d_in[3];
  const float* mpb  = (const float*)d_in[4];
  const float* msgw = (const float*)d_in[5];
  const float* msgb = (const float*)d_in[6];
  const float* e1w  = (const float*)d_in[7];
  const float* e1b  = (const float*)d_in[8];
  const float* e2w  = (const float*)d_in[9];
  const float* e2b  = (const float*)d_in[10];
  const float* root = (const float*)d_in[11];
  const float* convb= (const float*)d_in[12];
  float* out = (float*)d_out;

  char* ws = (char*)d_ws;
  unsigned short* h2 = (unsigned short*)ws; ws += (size_t)E_ * 128 * 2;
  unsigned short* Af = (unsigned short*)ws; ws += (size_t)4096 * 128 * 2;
  float* outa = (float*)ws; ws += (size_t)N_ * 64 * 4;
  float* ya   = (float*)ws; ws += (size_t)N_ * 64 * 4;
  float* outb = (float*)ws; ws += (size_t)N_ * 64 * 4;
  float* yb   = (float*)ws; ws += (size_t)N_ * 64 * 4;
  float* agg  = (float*)ws; ws += (size_t)N_ * 64 * 4;

  hipLaunchKernelGGL(k_prep_bf, dim3(256), dim3(256), 0, stream, e2w, Af);
  hipLaunchKernelGGL(k_zero, dim3((N_ * 64 + 255) / 256), dim3(256), 0, stream, agg, N_ * 64);
  hipLaunchKernelGGL(k_h2, dim3((E_ + 255) / 256), dim3(256), 0, stream, ea, e1w, e1b, h2);
  hipLaunchKernelGGL(k_node_in, dim3(N_ / 16), dim3(256), 0, stream, nfm, mpw, mpb, e2b, outa, ya);

  float* oc = outa; float* yc = ya; float* on = outb; float* yv = yb;
  for (int s = 0; s < 3; ++s) {
    hipLaunchKernelGGL(k_msgs, dim3((E_ + 127) / 128), dim3(512), 0, stream, oc, yc, h2, Af, ei, agg);
    hipLaunchKernelGGL(k_update, dim3(N_ / 16), dim3(256), 0, stream, oc, agg, root, convb,
                       msgw, msgb, e2b, nfm, (s == 2) ? 1 : 0, on, yv, out);
    float* tp;
    tp = oc; oc = on; on = tp;
    tp = yc; yc = yv; yv = tp;
  }
}